// Round 1
// baseline (194.587 us; speedup 1.0000x reference)
//
#include <hip/hip_runtime.h>
#include <float.h>
#include <math.h>

// Problem constants (from reference)
#define NA_LOG2 20                    // NA = 1048576
#define NB_ 4
#define ROWS (NB_ << NA_LOG2)         // 4194304 rows of probs (3 floats each)
#define B1 1024                       // pass-1 blocks (256 per batch)
#define T1 256
#define ROWS_PER_BLOCK (ROWS / B1)    // 4096
#define BLOCKS_PER_BATCH (B1 / NB_)   // 256
#define ITERS (ROWS_PER_BLOCK / (T1 * 4))  // 4

// strict total order: higher score wins, ties -> lower flat index
__device__ __forceinline__ bool better(float sa, int ia, float sb, int ib) {
    return (sa > sb) || ((sa == sb) && (ia < ib));
}

// merge sorted top2 (b1>=b2) into sorted top2 (a1>=a2)
__device__ __forceinline__ void merge2(float& a1s, int& a1i, float& a2s, int& a2i,
                                       float b1s, int b1i, float b2s, int b2i)
{
    if (better(b1s, b1i, a1s, a1i)) {
        if (better(a1s, a1i, b2s, b2i)) { a2s = a1s; a2i = a1i; }
        else                            { a2s = b2s; a2i = b2i; }
        a1s = b1s; a1i = b1i;
    } else if (better(b1s, b1i, a2s, a2i)) {
        a2s = b1s; a2i = b1i;
    }
}

#define UPD(sa, ia, sb, ib, s, i)                                        \
    do {                                                                 \
        if (better((s), (i), (sa), (ia))) {                              \
            (sb) = (sa); (ib) = (ia); (sa) = (s); (ia) = (i);            \
        } else if (better((s), (i), (sb), (ib))) {                       \
            (sb) = (s); (ib) = (i);                                      \
        }                                                                \
    } while (0)

// Pass 1: per-block top-2 for class1 and class2 (block lies entirely in one batch).
// ws layout: wsS/wsI indexed by block*4 + cls*2 + entry.
__global__ __launch_bounds__(T1) void topk_pass1(const float* __restrict__ probs,
                                                 float* __restrict__ wsS,
                                                 int* __restrict__ wsI)
{
    const int tid = threadIdx.x;
    const int bb = blockIdx.x;

    float s1a = -FLT_MAX, s1b = -FLT_MAX, s2a = -FLT_MAX, s2b = -FLT_MAX;
    int   i1a = 0x7fffffff, i1b = 0x7fffffff, i2a = 0x7fffffff, i2b = 0x7fffffff;

    const float4* p4 = (const float4*)probs;
    const int baseRow = bb * ROWS_PER_BLOCK;

#pragma unroll
    for (int k = 0; k < ITERS; ++k) {
        const int row0 = baseRow + (k * T1 + tid) * 4;      // 4 consecutive rows
        const float4* p = p4 + ((row0 * 3) >> 2);           // row0*3 floats, 16B aligned
        float4 v0 = p[0];
        float4 v1 = p[1];
        float4 v2 = p[2];
        const int f = row0 * 2;                              // flat fg index base
        // 12 floats = rows r..r+3, col pattern [0,1,2] repeating; col1->class1, col2->class2
        UPD(s1a, i1a, s1b, i1b, v0.y, f + 0);   // r+0 class1
        UPD(s2a, i2a, s2b, i2b, v0.z, f + 1);   // r+0 class2
        UPD(s1a, i1a, s1b, i1b, v1.x, f + 2);   // r+1 class1
        UPD(s2a, i2a, s2b, i2b, v1.y, f + 3);   // r+1 class2
        UPD(s1a, i1a, s1b, i1b, v1.w, f + 4);   // r+2 class1
        UPD(s2a, i2a, s2b, i2b, v2.x, f + 5);   // r+2 class2
        UPD(s1a, i1a, s1b, i1b, v2.z, f + 6);   // r+3 class1
        UPD(s2a, i2a, s2b, i2b, v2.w, f + 7);   // r+3 class2
    }

    // wave (64-lane) butterfly reduce of both top2 structs
#pragma unroll
    for (int m = 1; m < 64; m <<= 1) {
        float o1s = __shfl_xor(s1a, m); int o1i = __shfl_xor(i1a, m);
        float o2s = __shfl_xor(s1b, m); int o2i = __shfl_xor(i1b, m);
        merge2(s1a, i1a, s1b, i1b, o1s, o1i, o2s, o2i);
        o1s = __shfl_xor(s2a, m); o1i = __shfl_xor(i2a, m);
        o2s = __shfl_xor(s2b, m); o2i = __shfl_xor(i2b, m);
        merge2(s2a, i2a, s2b, i2b, o1s, o1i, o2s, o2i);
    }

    __shared__ float ls[4][4];
    __shared__ int   li[4][4];
    const int wave = tid >> 6, lane = tid & 63;
    if (lane == 0) {
        ls[wave][0] = s1a; li[wave][0] = i1a;
        ls[wave][1] = s1b; li[wave][1] = i1b;
        ls[wave][2] = s2a; li[wave][2] = i2a;
        ls[wave][3] = s2b; li[wave][3] = i2b;
    }
    __syncthreads();
    if (tid == 0) {
        // thread 0 still holds wave 0's result in registers; fold in waves 1..3
        for (int wv = 1; wv < 4; ++wv) {
            merge2(s1a, i1a, s1b, i1b, ls[wv][0], li[wv][0], ls[wv][1], li[wv][1]);
            merge2(s2a, i2a, s2b, i2b, ls[wv][2], li[wv][2], ls[wv][3], li[wv][3]);
        }
        const int base = bb * 4;
        wsS[base + 0] = s1a; wsI[base + 0] = i1a;
        wsS[base + 1] = s1b; wsI[base + 1] = i1b;
        wsS[base + 2] = s2a; wsI[base + 2] = i2a;
        wsS[base + 3] = s2b; wsI[base + 3] = i2b;
    }
}

// Pass 2: one block. Wave w reduces group w (batch=w>>1, class bit=w&1) over the
// 512 per-block candidates; thread 0 sorts the 16 winners (score desc, idx asc)
// = the reference's keep-order; 16 threads emit the 16 output rows.
__global__ __launch_bounds__(512) void topk_pass2(const float* __restrict__ wsS,
                                                  const int* __restrict__ wsI,
                                                  const float* __restrict__ anchors,
                                                  const float* __restrict__ deltas,
                                                  float* __restrict__ out)
{
    __shared__ float g_s[16];
    __shared__ int   g_i[16];
    const int tid = threadIdx.x;
    const int wave = tid >> 6, lane = tid & 63;
    const int batch = wave >> 1, clsbit = wave & 1;

    float sa = -FLT_MAX, sb = -FLT_MAX;
    int   ia = 0x7fffffff, ib = 0x7fffffff;
#pragma unroll
    for (int j = 0; j < (2 * BLOCKS_PER_BATCH) / 64; ++j) {  // 8 candidates/lane
        const int q = lane + j * 64;                          // 0..511
        const int blk = batch * BLOCKS_PER_BATCH + (q >> 1);
        const int e = q & 1;
        const int idx = blk * 4 + clsbit * 2 + e;
        const float s = wsS[idx];
        const int   i = wsI[idx];
        UPD(sa, ia, sb, ib, s, i);
    }
#pragma unroll
    for (int m = 1; m < 64; m <<= 1) {
        float o1s = __shfl_xor(sa, m); int o1i = __shfl_xor(ia, m);
        float o2s = __shfl_xor(sb, m); int o2i = __shfl_xor(ib, m);
        merge2(sa, ia, sb, ib, o1s, o1i, o2s, o2i);
    }
    if (lane == 0) {
        g_s[wave * 2 + 0] = sa; g_i[wave * 2 + 0] = ia;
        g_s[wave * 2 + 1] = sb; g_i[wave * 2 + 1] = ib;
    }
    __syncthreads();

    if (tid == 0) {
        // insertion sort, descending by (score, -idx) == keep order
        for (int a = 1; a < 16; ++a) {
            float s = g_s[a]; int ix = g_i[a];
            int b = a - 1;
            while (b >= 0 && better(s, ix, g_s[b], g_i[b])) {
                g_s[b + 1] = g_s[b]; g_i[b + 1] = g_i[b]; --b;
            }
            g_s[b + 1] = s; g_i[b + 1] = ix;
        }
    }
    __syncthreads();

    if (tid < 16) {
        const float scale[6] = {256.f, 256.f, 256.f, 256.f, 128.f, 128.f};
        const float stdv[6]  = {0.1f, 0.1f, 0.1f, 0.2f, 0.2f, 0.2f};
        const int flat = g_i[tid];
        const float score = g_s[tid];
        const int prop = flat >> 1;
        const int cls = (flat & 1) + 1;
        const int b = prop >> NA_LOG2;
        const int ar = prop & ((1 << NA_LOG2) - 1);   // anchors_rep index mod NA

        float anc[6], dlt[6];
#pragma unroll
        for (int k = 0; k < 6; ++k) {
            anc[k] = floorf(anchors[ar * 6 + k] / scale[k]);
            dlt[k] = deltas[prop * 6 + k] * stdv[k];
        }
        float h = anc[2] - anc[0];
        float w = anc[3] - anc[1];
        float d = anc[5] - anc[4];
        float cy = anc[0] + 0.5f * h + dlt[0] * h;
        float cx = anc[1] + 0.5f * w + dlt[1] * w;
        float cz = anc[4] + 0.5f * d + dlt[2] * d;
        h *= expf(dlt[3]);
        w *= expf(dlt[4]);
        d *= expf(dlt[5]);
        const float y1 = cy - 0.5f * h, x1 = cx - 0.5f * w, z1 = cz - 0.5f * d;
        const float box[6] = {y1, x1, y1 + h, x1 + w, z1, z1 + d};

        float* o = out + tid * 9;
#pragma unroll
        for (int k = 0; k < 6; ++k) {
            float bx = box[k] * scale[k];
            bx = fminf(fmaxf(bx, 0.f), scale[k]);
            o[k] = rintf(bx);               // jnp.round = round-half-to-even
        }
        o[6] = (float)b;
        o[7] = (float)cls;
        o[8] = score;
    }
}

extern "C" void kernel_launch(void* const* d_in, const int* in_sizes, int n_in,
                              void* d_out, int out_size, void* d_ws, size_t ws_size,
                              hipStream_t stream)
{
    // setup_inputs order: anchors, probs, deltas, batch_ixs
    const float* anchors = (const float*)d_in[0];
    const float* probs   = (const float*)d_in[1];
    const float* deltas  = (const float*)d_in[2];
    // batch_ixs (d_in[3]) is closed-form (prop >> 20); unused.

    float* wsS = (float*)d_ws;                                   // 4096 floats
    int*   wsI = (int*)((char*)d_ws + B1 * 4 * sizeof(float));   // 4096 ints

    topk_pass1<<<dim3(B1), dim3(T1), 0, stream>>>(probs, wsS, wsI);
    topk_pass2<<<dim3(1), dim3(512), 0, stream>>>(wsS, wsI, anchors, deltas, (float*)d_out);
}